// Round 1
// baseline (434431.982 us; speedup 1.0000x reference)
//
#include <hip/hip_runtime.h>

// SimpleGRU: B=64, S=512, D=H=1024, L=2, fp32.
// R1 baseline: persistent kernel, custom device-scope grid barrier,
// fp32 VALU compute, W streamed from L2/LLC.
// Mapping: 128 blocks x 256 threads = 32768 threads; thread owns column n
// (0..1023) and two batch rows (b0, b0+32) -> W loaded once, used twice.
// ws layout: [0,4KB) barrier counters; [4KB) h[64][1024] f32;
//            [266240) rh[64][1024] f32; [1MB) X1[512][64][1024] f32 (128MB).
// Requires ws_size >= ~130 MB.

#define B_ 64
#define S_ 512
#define D_ 1024
#define H_ 1024
#define DH_ 2048
#define NBLK 128
#define TPB 256
#define NTHREADS (NBLK * TPB)   // 32768

__device__ __forceinline__ void gbar(int* cnt, int* gen) {
    __threadfence();            // release my global writes (device scope)
    __syncthreads();
    if (threadIdx.x == 0) {
        int g = __hip_atomic_load(gen, __ATOMIC_ACQUIRE, __HIP_MEMORY_SCOPE_AGENT);
        if (__hip_atomic_fetch_add(cnt, 1, __ATOMIC_ACQ_REL, __HIP_MEMORY_SCOPE_AGENT)
            == NBLK - 1) {
            __hip_atomic_store(cnt, 0, __ATOMIC_RELAXED, __HIP_MEMORY_SCOPE_AGENT);
            __hip_atomic_fetch_add(gen, 1, __ATOMIC_RELEASE, __HIP_MEMORY_SCOPE_AGENT);
        } else {
            while (__hip_atomic_load(gen, __ATOMIC_ACQUIRE, __HIP_MEMORY_SCOPE_AGENT) == g) {
                __builtin_amdgcn_s_sleep(2);
            }
        }
    }
    __syncthreads();
    __threadfence();            // acquire side
}

__device__ __forceinline__ float sigmoidf_(float v) {
    return 1.0f / (1.0f + expf(-v));
}

__global__ __launch_bounds__(TPB, 1) void gru_seq(
    const float* __restrict__ x,   // [B,S,D]
    const float* __restrict__ Wr,  // [L,DH,H]
    const float* __restrict__ Wz,
    const float* __restrict__ Wh,
    const float* __restrict__ br,  // [L,H]
    const float* __restrict__ bz,
    const float* __restrict__ bh,
    float* __restrict__ out,       // [B,S,H]
    float* __restrict__ h,         // [64][1024]
    float* __restrict__ rh,        // [64][1024]
    float* __restrict__ X1,        // [S][B][H] layer-1 output
    int* __restrict__ bcnt, int* __restrict__ bgen)
{
    const int tid = blockIdx.x * TPB + threadIdx.x;  // 0..32767
    const int n  = tid & (H_ - 1);
    const int b0 = tid >> 10;                        // 0..31
    const int b1 = b0 + 32;

    for (int l = 0; l < 2; ++l) {
        const float* WrL = Wr + (size_t)l * DH_ * H_;
        const float* WzL = Wz + (size_t)l * DH_ * H_;
        const float* WhL = Wh + (size_t)l * DH_ * H_;
        const float brv = br[l * H_ + n];
        const float bzv = bz[l * H_ + n];
        const float bhv = bh[l * H_ + n];

        // zero h for this layer (32768 threads cover 65536 elems)
        h[tid] = 0.0f;
        h[tid + NTHREADS] = 0.0f;
        gbar(bcnt, bgen);

        for (int t = 0; t < S_; ++t) {
            const float *x0, *x1;
            if (l == 0) {
                x0 = x + ((size_t)b0 * S_ + t) * D_;   // x[b][t][:]
                x1 = x + ((size_t)b1 * S_ + t) * D_;
            } else {
                x0 = X1 + ((size_t)t * B_ + b0) * H_;  // X1[t][b][:]
                x1 = X1 + ((size_t)t * B_ + b1) * H_;
            }
            const float* h0p = h + b0 * H_;
            const float* h1p = h + b1 * H_;

            // ---- Phase A: r and z pre-activations (K = 2048) ----
            float ar0 = 0.f, az0 = 0.f, ar1 = 0.f, az1 = 0.f;
            const float* wr = WrL + n;
            const float* wz = WzL + n;
            #pragma unroll 4
            for (int k = 0; k < D_; ++k) {
                float w_r = wr[(size_t)k * H_];
                float w_z = wz[(size_t)k * H_];
                float v0 = x0[k], v1 = x1[k];
                ar0 = fmaf(v0, w_r, ar0); az0 = fmaf(v0, w_z, az0);
                ar1 = fmaf(v1, w_r, ar1); az1 = fmaf(v1, w_z, az1);
            }
            const float* wrh = wr + (size_t)D_ * H_;
            const float* wzh = wz + (size_t)D_ * H_;
            #pragma unroll 4
            for (int k = 0; k < H_; ++k) {
                float w_r = wrh[(size_t)k * H_];
                float w_z = wzh[(size_t)k * H_];
                float v0 = h0p[k], v1 = h1p[k];
                ar0 = fmaf(v0, w_r, ar0); az0 = fmaf(v0, w_z, az0);
                ar1 = fmaf(v1, w_r, ar1); az1 = fmaf(v1, w_z, az1);
            }
            float hold0 = h0p[n], hold1 = h1p[n];
            float r0 = sigmoidf_(ar0 + brv);
            float r1 = sigmoidf_(ar1 + brv);
            float z0 = sigmoidf_(az0 + bzv);
            float z1 = sigmoidf_(az1 + bzv);
            rh[b0 * H_ + n] = r0 * hold0;
            rh[b1 * H_ + n] = r1 * hold1;
            gbar(bcnt, bgen);   // rh visible to all before Phase B

            // ---- Phase B: n gate (K = 2048 over [x, r*h]) + h update ----
            float an0 = 0.f, an1 = 0.f;
            const float* wh = WhL + n;
            #pragma unroll 4
            for (int k = 0; k < D_; ++k) {
                float w_h = wh[(size_t)k * H_];
                an0 = fmaf(x0[k], w_h, an0);
                an1 = fmaf(x1[k], w_h, an1);
            }
            const float* whh = wh + (size_t)D_ * H_;
            const float* rh0 = rh + b0 * H_;
            const float* rh1 = rh + b1 * H_;
            #pragma unroll 4
            for (int k = 0; k < H_; ++k) {
                float w_h = whh[(size_t)k * H_];
                an0 = fmaf(rh0[k], w_h, an0);
                an1 = fmaf(rh1[k], w_h, an1);
            }
            float ng0 = tanhf(an0 + bhv);
            float ng1 = tanhf(an1 + bhv);
            float hn0 = (1.0f - z0) * ng0 + z0 * hold0;
            float hn1 = (1.0f - z1) * ng1 + z1 * hold1;
            h[b0 * H_ + n] = hn0;
            h[b1 * H_ + n] = hn1;
            if (l == 0) {
                X1[((size_t)t * B_ + b0) * H_ + n] = hn0;
                X1[((size_t)t * B_ + b1) * H_ + n] = hn1;
            } else {
                out[((size_t)b0 * S_ + t) * H_ + n] = hn0;
                out[((size_t)b1 * S_ + t) * H_ + n] = hn1;
            }
            gbar(bcnt, bgen);   // h visible before next step's Phase A
        }
    }
}

extern "C" void kernel_launch(void* const* d_in, const int* in_sizes, int n_in,
                              void* d_out, int out_size, void* d_ws, size_t ws_size,
                              hipStream_t stream) {
    const float* x  = (const float*)d_in[0];
    const float* Wr = (const float*)d_in[1];
    const float* Wz = (const float*)d_in[2];
    const float* Wh = (const float*)d_in[3];
    const float* br = (const float*)d_in[4];
    const float* bz = (const float*)d_in[5];
    const float* bh = (const float*)d_in[6];
    float* out = (float*)d_out;

    char* ws = (char*)d_ws;
    int*   bcnt = (int*)(ws + 0);
    int*   bgen = (int*)(ws + 64);
    float* h    = (float*)(ws + 4096);                     // 256 KB
    float* rh   = (float*)(ws + 4096 + 262144);            // 256 KB
    float* X1   = (float*)(ws + (1 << 20));                // 128 MB

    // ws is re-poisoned 0xAA before every timed call: zero barrier counters.
    hipMemsetAsync(d_ws, 0, 4096, stream);

    gru_seq<<<NBLK, TPB, 0, stream>>>(x, Wr, Wz, Wh, br, bz, bh,
                                      out, h, rh, X1, bcnt, bgen);
}

// Round 2
// 275669.165 us; speedup vs baseline: 1.5759x; 1.5759x over previous
//
#include <hip/hip_runtime.h>

// SimpleGRU R2: persistent MFMA kernel, LDS-resident split-bf16 weights.
// B=64, S=512, D=H=1024, L=2. Grid 256x256 (1 block/CU, co-resident).
// Block (ks,nt): ks=blockIdx>>5 (K-slice of 256), nt=blockIdx&31 (N-tile).
// Phase A: rz GEMM [64x2048]@[2048x2048] -> partials P_rz[ks][col][m]
// Phase B: n  GEMM [64x2048]@[2048x1024] -> partials P_n
// Split bf16: v = hi + lo; D += Ahi*Whi + Alo*Whi + Ahi*Wlo  (~fp32 acc).

#define TPB 256
#define NBLK 256
#define NGRP 8
#define B_ 64
#define S_ 512
#define KTOT 2048
#define H_ 1024

typedef float f32x4 __attribute__((ext_vector_type(4)));
typedef short short8 __attribute__((ext_vector_type(8)));

// LDS offsets (in shorts); total 81920 shorts = 163840 B = 160 KiB exactly.
#define WRZ_HI 0
#define WRZ_LO 16384
#define WN_HI  32768
#define WN_LO  40960
#define A_HI   49152
#define A_LO   65536

__device__ __forceinline__ short f2bf(float f) {
    unsigned u = __float_as_uint(f);
    u += 0x7fffu + ((u >> 16) & 1u);
    return (short)(u >> 16);
}
__device__ __forceinline__ float bf2f(short s) {
    return __uint_as_float(((unsigned)(unsigned short)s) << 16);
}
__device__ __forceinline__ float sigm(float v) { return 1.0f / (1.0f + expf(-v)); }

__device__ __forceinline__ void gbar(unsigned* bar, int grp) {
    __threadfence();
    __syncthreads();
    if (threadIdx.x == 0) {
        unsigned* cnt  = bar + grp * 32;          // 128-B spaced
        unsigned* gen  = bar + 256 + grp * 32;    // byte 1024+
        unsigned* ccnt = bar + 512;               // byte 2048
        unsigned g = __hip_atomic_load(gen, __ATOMIC_RELAXED, __HIP_MEMORY_SCOPE_AGENT);
        if (__hip_atomic_fetch_add(cnt, 1u, __ATOMIC_ACQ_REL, __HIP_MEMORY_SCOPE_AGENT)
            == (NBLK / NGRP) - 1) {
            __hip_atomic_store(cnt, 0u, __ATOMIC_RELAXED, __HIP_MEMORY_SCOPE_AGENT);
            if (__hip_atomic_fetch_add(ccnt, 1u, __ATOMIC_ACQ_REL, __HIP_MEMORY_SCOPE_AGENT)
                == NGRP - 1) {
                __hip_atomic_store(ccnt, 0u, __ATOMIC_RELAXED, __HIP_MEMORY_SCOPE_AGENT);
                #pragma unroll
                for (int i = 0; i < NGRP; ++i)
                    __hip_atomic_store(bar + 256 + i * 32, g + 1u,
                                       __ATOMIC_RELEASE, __HIP_MEMORY_SCOPE_AGENT);
            } else {
                while (__hip_atomic_load(gen, __ATOMIC_ACQUIRE, __HIP_MEMORY_SCOPE_AGENT) == g)
                    __builtin_amdgcn_s_sleep(1);
            }
        } else {
            while (__hip_atomic_load(gen, __ATOMIC_ACQUIRE, __HIP_MEMORY_SCOPE_AGENT) == g)
                __builtin_amdgcn_s_sleep(1);
        }
    }
    __syncthreads();
}

__global__ __launch_bounds__(TPB, 1) void gru_mfma(
    const float* __restrict__ x,    // [64][512][1024]
    const float* __restrict__ Wr,   // [2][2048][1024]
    const float* __restrict__ Wz,
    const float* __restrict__ Wh,
    const float* __restrict__ pbr,  // [2][1024]
    const float* __restrict__ pbz,
    const float* __restrict__ pbh,
    float* __restrict__ out,        // [64][512][1024]
    float* __restrict__ P_rz,       // [8][2048][64]
    float* __restrict__ P_n,        // [8][1024][64]
    float* __restrict__ h_mk,       // [64][1024]  (k-contiguous, for staging)
    float* __restrict__ h_t,        // [1024][64]  (m-contiguous, for reduces)
    float* __restrict__ rhb,        // [64][1024]
    float* __restrict__ z_t,        // [1024][64]
    float* __restrict__ X1,         // [512][64][1024]
    unsigned* __restrict__ bar)
{
    __shared__ short lds[81920];
    const int ks  = blockIdx.x >> 5;   // 0..7
    const int nt  = blockIdx.x & 31;   // 0..31
    const int grp = blockIdx.x & 7;
    const int lane = threadIdx.x & 63;
    const int wave = threadIdx.x >> 6;
    const int gtid = blockIdx.x * TPB + threadIdx.x;  // 0..65535

    for (int l = 0; l < 2; ++l) {
        // ---- stage weights for this layer into LDS (hi/lo bf16, frag order) ----
        {
            const float* Wg = (nt < 16) ? Wr : Wz;
            const int col0 = (nt & 15) * 64;
            for (int s = threadIdx.x; s < 2048; s += TPB) {
                int ln = s & 63, ns = (s >> 6) & 3, kc = s >> 8;
                int n  = col0 + ns * 16 + (ln & 15);
                int kr = ks * 256 + kc * 32 + ((ln >> 4) << 3);
                short8 hi, lo;
                #pragma unroll
                for (int j = 0; j < 8; ++j) {
                    float v = Wg[((size_t)(l * KTOT + kr + j)) * H_ + n];
                    short hb = f2bf(v);
                    hi[j] = hb; lo[j] = f2bf(v - bf2f(hb));
                }
                *(short8*)&lds[WRZ_HI + s * 8] = hi;
                *(short8*)&lds[WRZ_LO + s * 8] = lo;
            }
            for (int s = threadIdx.x; s < 1024; s += TPB) {
                int ln = s & 63, ns = (s >> 6) & 1, kc = s >> 7;
                int n  = nt * 32 + ns * 16 + (ln & 15);
                int kr = ks * 256 + kc * 32 + ((ln >> 4) << 3);
                short8 hi, lo;
                #pragma unroll
                for (int j = 0; j < 8; ++j) {
                    float v = Wh[((size_t)(l * KTOT + kr + j)) * H_ + n];
                    short hb = f2bf(v);
                    hi[j] = hb; lo[j] = f2bf(v - bf2f(hb));
                }
                *(short8*)&lds[WN_HI + s * 8] = hi;
                *(short8*)&lds[WN_LO + s * 8] = lo;
            }
        }
        // zero h (both layouts)
        h_mk[gtid] = 0.0f;
        h_t[gtid]  = 0.0f;
        gbar(bar, grp);

        for (int t = 0; t < S_; ++t) {
            // ---- stage A slice [64m x 256k] hi/lo (x|X1 for k<1024, h for k>=1024)
            for (int s = threadIdx.x; s < 2048; s += TPB) {
                int ln = s & 63, ms = (s >> 6) & 3, kc = s >> 8;
                int m  = ms * 16 + (ln & 15);
                int kg = ks * 256 + kc * 32 + ((ln >> 4) << 3);
                const float* src;
                if (kg < 1024)
                    src = (l == 0) ? x  + ((size_t)(m * S_ + t)) * H_ + kg
                                   : X1 + ((size_t)(t * B_ + m)) * H_ + kg;
                else
                    src = h_mk + m * H_ + (kg - 1024);
                float4 v0 = *(const float4*)src;
                float4 v1 = *(const float4*)(src + 4);
                float vv[8] = {v0.x, v0.y, v0.z, v0.w, v1.x, v1.y, v1.z, v1.w};
                short8 hi, lo;
                #pragma unroll
                for (int j = 0; j < 8; ++j) {
                    short hb = f2bf(vv[j]);
                    hi[j] = hb; lo[j] = f2bf(vv[j] - bf2f(hb));
                }
                *(short8*)&lds[A_HI + s * 8] = hi;
                *(short8*)&lds[A_LO + s * 8] = lo;
            }
            __syncthreads();

            // ---- Phase A GEMM: wave owns Nsub=wave; 4 Msubs; K=256 ----
            {
                f32x4 acc[4] = {{0,0,0,0},{0,0,0,0},{0,0,0,0},{0,0,0,0}};
                #pragma unroll
                for (int kc = 0; kc < 8; ++kc) {
                    short8 bfh = *(const short8*)&lds[WRZ_HI + ((kc*4 + wave)*64 + lane)*8];
                    short8 bfl = *(const short8*)&lds[WRZ_LO + ((kc*4 + wave)*64 + lane)*8];
                    #pragma unroll
                    for (int ms = 0; ms < 4; ++ms) {
                        short8 afh = *(const short8*)&lds[A_HI + ((kc*4 + ms)*64 + lane)*8];
                        short8 afl = *(const short8*)&lds[A_LO + ((kc*4 + ms)*64 + lane)*8];
                        acc[ms] = __builtin_amdgcn_mfma_f32_16x16x32_bf16(afh, bfh, acc[ms], 0,0,0);
                        acc[ms] = __builtin_amdgcn_mfma_f32_16x16x32_bf16(afl, bfh, acc[ms], 0,0,0);
                        acc[ms] = __builtin_amdgcn_mfma_f32_16x16x32_bf16(afh, bfl, acc[ms], 0,0,0);
                    }
                }
                int colg = nt * 64 + wave * 16 + (lane & 15);
                int q = lane >> 4;
                #pragma unroll
                for (int ms = 0; ms < 4; ++ms)
                    *(f32x4*)&P_rz[((size_t)(ks * 2048 + colg)) * 64 + ms * 16 + q * 4] = acc[ms];
            }
            gbar(bar, grp);

            // ---- reduce A: sigmoid gates; write rh (m-major) and z (t-major) ----
            #pragma unroll
            for (int rep = 0; rep < 2; ++rep) {
                int idx = rep * 65536 + gtid;
                int m = idx & 63, col = idx >> 6;   // col 0..2047
                float ssum = 0.f;
                #pragma unroll
                for (int k2 = 0; k2 < 8; ++k2)
                    ssum += P_rz[((size_t)(k2 * 2048 + col)) * 64 + m];
                if (col < 1024) {
                    float rr = sigm(ssum + pbr[l * H_ + col]);
                    rhb[m * H_ + col] = rr * h_t[col * 64 + m];
                } else {
                    int c = col - 1024;
                    z_t[c * 64 + m] = sigm(ssum + pbz[l * H_ + c]);
                }
            }
            gbar(bar, grp);

            // ---- restage A for phase B (only h-part slices: rh) ----
            if (ks >= 4) {
                for (int s = threadIdx.x; s < 2048; s += TPB) {
                    int ln = s & 63, ms = (s >> 6) & 3, kc = s >> 8;
                    int m  = ms * 16 + (ln & 15);
                    int kg = ks * 256 + kc * 32 + ((ln >> 4) << 3);
                    const float* src = rhb + m * H_ + (kg - 1024);
                    float4 v0 = *(const float4*)src;
                    float4 v1 = *(const float4*)(src + 4);
                    float vv[8] = {v0.x, v0.y, v0.z, v0.w, v1.x, v1.y, v1.z, v1.w};
                    short8 hi, lo;
                    #pragma unroll
                    for (int j = 0; j < 8; ++j) {
                        short hb = f2bf(vv[j]);
                        hi[j] = hb; lo[j] = f2bf(vv[j] - bf2f(hb));
                    }
                    *(short8*)&lds[A_HI + s * 8] = hi;
                    *(short8*)&lds[A_LO + s * 8] = lo;
                }
            }
            __syncthreads();

            // ---- Phase B GEMM: N=32 (2 Nsubs); wave -> (nsb, Msub-pair) ----
            {
                int nsb = wave & 1, mh = wave >> 1;
                f32x4 acc[2] = {{0,0,0,0},{0,0,0,0}};
                #pragma unroll
                for (int kc = 0; kc < 8; ++kc) {
                    short8 bfh = *(const short8*)&lds[WN_HI + ((kc*2 + nsb)*64 + lane)*8];
                    short8 bfl = *(const short8*)&lds[WN_LO + ((kc*2 + nsb)*64 + lane)*8];
                    #pragma unroll
                    for (int i = 0; i < 2; ++i) {
                        int ms = mh * 2 + i;
                        short8 afh = *(const short8*)&lds[A_HI + ((kc*4 + ms)*64 + lane)*8];
                        short8 afl = *(const short8*)&lds[A_LO + ((kc*4 + ms)*64 + lane)*8];
                        acc[i] = __builtin_amdgcn_mfma_f32_16x16x32_bf16(afh, bfh, acc[i], 0,0,0);
                        acc[i] = __builtin_amdgcn_mfma_f32_16x16x32_bf16(afl, bfh, acc[i], 0,0,0);
                        acc[i] = __builtin_amdgcn_mfma_f32_16x16x32_bf16(afh, bfl, acc[i], 0,0,0);
                    }
                }
                int coln = nt * 32 + nsb * 16 + (lane & 15);
                int q = lane >> 4;
                #pragma unroll
                for (int i = 0; i < 2; ++i)
                    *(f32x4*)&P_n[((size_t)(ks * 1024 + coln)) * 64 + (mh*2 + i)*16 + q*4] = acc[i];
            }
            gbar(bar, grp);

            // ---- reduce B: tanh, h update, output ----
            {
                int m = gtid & 63, col = gtid >> 6;  // col 0..1023
                float ssum = 0.f;
                #pragma unroll
                for (int k2 = 0; k2 < 8; ++k2)
                    ssum += P_n[((size_t)(k2 * 1024 + col)) * 64 + m];
                float ng = tanhf(ssum + pbh[l * H_ + col]);
                float zz = z_t[col * 64 + m];
                float ho = h_t[col * 64 + m];
                float hn = (1.0f - zz) * ng + zz * ho;
                h_t[col * 64 + m] = hn;
                h_mk[m * H_ + col] = hn;
                if (l == 0) X1[((size_t)(t * B_ + m)) * H_ + col] = hn;
                else        out[((size_t)(m * S_ + t)) * H_ + col] = hn;
            }
            gbar(bar, grp);
        }
    }
}

extern "C" void kernel_launch(void* const* d_in, const int* in_sizes, int n_in,
                              void* d_out, int out_size, void* d_ws, size_t ws_size,
                              hipStream_t stream) {
    const float* x  = (const float*)d_in[0];
    const float* Wr = (const float*)d_in[1];
    const float* Wz = (const float*)d_in[2];
    const float* Wh = (const float*)d_in[3];
    const float* br = (const float*)d_in[4];
    const float* bz = (const float*)d_in[5];
    const float* bh = (const float*)d_in[6];
    float* out = (float*)d_out;

    char* ws = (char*)d_ws;
    unsigned* bar = (unsigned*)ws;                          // 4 KB
    float* P_rz = (float*)(ws + 4096);                      // 4 MB
    float* P_n  = (float*)(ws + 4096 + 4194304);            // 2 MB
    float* h_mk = (float*)(ws + 6295552);                   // 256 KB
    float* h_t  = (float*)(ws + 6557696);                   // 256 KB
    float* rhb  = (float*)(ws + 6819840);                   // 256 KB
    float* z_t  = (float*)(ws + 7081984);                   // 256 KB
    float* X1   = (float*)(ws + 7344128);                   // 128 MB

    hipMemsetAsync(d_ws, 0, 4096, stream);   // barrier state must start at 0
    gru_mfma<<<NBLK, TPB, 0, stream>>>(x, Wr, Wz, Wh, br, bz, bh, out,
                                       P_rz, P_n, h_mk, h_t, rhb, z_t, X1, bar);
}

// Round 3
// 67884.827 us; speedup vs baseline: 6.3995x; 4.0608x over previous
//
#include <hip/hip_runtime.h>

// SimpleGRU R3: full-K-per-block MFMA, fence-free cross-XCD exchange.
// 256 blocks x 256 thr; block b owns output cols c0=b*4 (.. +3) of r,z,n.
// Weights LDS-resident split-bf16 (hi/lo), 96 KB. A staged per 256-K chunk
// (64 KB LDS): x-part via fp32 loads + convert (cacheable, L2-warm);
// h/rh-part via global_load_lds aux=SC0|SC1 from pre-split bf16 pub arrays
// (bypass L1/L2 -> always coherent, no fences, no buffer_inv).
// 2 relaxed-atomic grid barriers per step.

#define TPB 256
#define NBLK 256
#define B_ 64
#define S_ 512
#define H_ 1024
#define KTOT 2048

typedef float f32x4 __attribute__((ext_vector_type(4)));
typedef short short8 __attribute__((ext_vector_type(8)));

// LDS (shorts): total 81920 = 160 KiB exactly
#define WRZ_HI 0
#define WRZ_LO 16384
#define WN_HI  32768
#define WN_LO  40960
#define A_HI   49152
#define A_LO   65536

#define GLL(gp, lp) \
    __builtin_amdgcn_global_load_lds((__attribute__((address_space(1))) const void*)(const void*)(gp), \
                                     (__attribute__((address_space(3))) void*)(void*)(lp), 16, 0, 0x11)

__device__ __forceinline__ unsigned short f2bf(float f) {
    unsigned u = __float_as_uint(f);
    u += 0x7fffu + ((u >> 16) & 1u);
    return (unsigned short)(u >> 16);
}
__device__ __forceinline__ float bf2f(unsigned short s) {
    return __uint_as_float(((unsigned)s) << 16);
}
__device__ __forceinline__ float sigm(float v) { return 1.0f / (1.0f + expf(-v)); }

__device__ __forceinline__ void store_short_bypass(const unsigned short* addr, unsigned short v) {
    asm volatile("global_store_short %0, %1, off sc0 sc1"
                 :: "v"((unsigned long long)(uintptr_t)addr), "v"((unsigned)v) : "memory");
}
__device__ __forceinline__ void waitcnt0() {
    asm volatile("s_waitcnt vmcnt(0)" ::: "memory");
}

// Two-level grid barrier, RELAXED atomics only (no cache maintenance).
__device__ __forceinline__ void gbar(unsigned* bar, int grp) {
    __syncthreads();   // drains each wave's vmcnt (incl. bypass stores) before arrival
    if (threadIdx.x == 0) {
        unsigned* cnt  = bar + grp * 32;
        unsigned* gen  = bar + 256 + grp * 32;
        unsigned* ccnt = bar + 512;
        unsigned g = __hip_atomic_load(gen, __ATOMIC_RELAXED, __HIP_MEMORY_SCOPE_AGENT);
        if (__hip_atomic_fetch_add(cnt, 1u, __ATOMIC_RELAXED, __HIP_MEMORY_SCOPE_AGENT) == 31u) {
            __hip_atomic_store(cnt, 0u, __ATOMIC_RELAXED, __HIP_MEMORY_SCOPE_AGENT);
            waitcnt0();  // cnt reset visible before ccnt bump
            if (__hip_atomic_fetch_add(ccnt, 1u, __ATOMIC_RELAXED, __HIP_MEMORY_SCOPE_AGENT) == 7u) {
                __hip_atomic_store(ccnt, 0u, __ATOMIC_RELAXED, __HIP_MEMORY_SCOPE_AGENT);
                waitcnt0();  // ccnt reset visible before gen bumps
                #pragma unroll
                for (int i = 0; i < 8; ++i)
                    __hip_atomic_store(bar + 256 + i * 32, g + 1u,
                                       __ATOMIC_RELAXED, __HIP_MEMORY_SCOPE_AGENT);
            } else {
                while (__hip_atomic_load(gen, __ATOMIC_RELAXED, __HIP_MEMORY_SCOPE_AGENT) == g)
                    __builtin_amdgcn_s_sleep(8);
            }
        } else {
            while (__hip_atomic_load(gen, __ATOMIC_RELAXED, __HIP_MEMORY_SCOPE_AGENT) == g)
                __builtin_amdgcn_s_sleep(8);
        }
    }
    __syncthreads();
}

__global__ __launch_bounds__(TPB, 1) void gru_fk(
    const float* __restrict__ x,    // [64][512][1024]
    const float* __restrict__ Wr,   // [2][2048][1024]
    const float* __restrict__ Wz,
    const float* __restrict__ Wh,
    const float* __restrict__ pbr,  // [2][1024]
    const float* __restrict__ pbz,
    const float* __restrict__ pbh,
    float* __restrict__ out,        // [64][512][1024]
    unsigned short* __restrict__ h_hi,   // [64][1024] bf16 (bypass-only)
    unsigned short* __restrict__ h_lo,
    unsigned short* __restrict__ rh_hi,
    unsigned short* __restrict__ rh_lo,
    float* __restrict__ hpriv,      // [256 blk][64][4]  (block-private, cacheable)
    float* __restrict__ zpriv,
    float* __restrict__ X1,         // [512][64][1024] fp32 (layer-1 out)
    unsigned* __restrict__ bar)
{
    __shared__ short lds[81920];
    const int lane = threadIdx.x & 63;
    const int wave = threadIdx.x >> 6;
    const int c0   = blockIdx.x << 2;          // 4 cols per block
    const int grp  = blockIdx.x & 7;
    float* hp = hpriv + (blockIdx.x << 8);
    float* zp = zpriv + (blockIdx.x << 8);

    const int q  = lane >> 4;       // quad 0..3
    const int jc = lane & 15;       // C/D col slot

    for (int l = 0; l < 2; ++l) {
        // ---- stage weights (once per layer): split bf16 hi/lo, compact B-frag order ----
        for (int g = threadIdx.x; g < 2048; g += TPB) {     // rz: 8 n-slots
            int n = g & 7, t2 = g >> 3, qq = t2 & 3, kk = t2 >> 2;
            int k = kk * 32 + qq * 8;
            int col = c0 + (n & 3);
            const float* Wg = (n < 4) ? Wr : Wz;
            short8 hi, lo;
            #pragma unroll
            for (int j = 0; j < 8; ++j) {
                float v = Wg[((size_t)(l * KTOT + k + j)) * H_ + col];
                unsigned short hb = f2bf(v);
                hi[j] = (short)hb; lo[j] = (short)f2bf(v - bf2f(hb));
            }
            *(short8*)&lds[WRZ_HI + g * 8] = hi;
            *(short8*)&lds[WRZ_LO + g * 8] = lo;
        }
        for (int g = threadIdx.x; g < 1024; g += TPB) {     // n-gate: 4 n-slots
            int n = g & 3, t2 = g >> 2, qq = t2 & 3, kk = t2 >> 2;
            int k = kk * 32 + qq * 8;
            int col = c0 + n;
            short8 hi, lo;
            #pragma unroll
            for (int j = 0; j < 8; ++j) {
                float v = Wh[((size_t)(l * KTOT + k + j)) * H_ + col];
                unsigned short hb = f2bf(v);
                hi[j] = (short)hb; lo[j] = (short)f2bf(v - bf2f(hb));
            }
            *(short8*)&lds[WN_HI + g * 8] = hi;
            *(short8*)&lds[WN_LO + g * 8] = lo;
        }
        // ---- init h = 0 (private + published) ----
        {
            int m = threadIdx.x & 63, cc = threadIdx.x >> 6;
            hp[(m << 2) | cc] = 0.0f;
            store_short_bypass(h_hi + m * H_ + c0 + cc, 0);
            store_short_bypass(h_lo + m * H_ + c0 + cc, 0);
        }
        gbar(bar, grp);

        const float brv = pbr[l * H_ + c0 + (jc & 3)];
        const float bzv = pbz[l * H_ + c0 + (jc & 3)];
        const float bhv = pbh[l * H_ + c0 + (jc & 3)];

        for (int t = 0; t < S_; ++t) {
            // =================== Phase A: r,z gates ===================
            f32x4 acc = {0.f, 0.f, 0.f, 0.f};
            for (int c = 0; c < 8; ++c) {
                if (c < 4) {   // x-part: fp32 load + split (cacheable)
                    for (int s = threadIdx.x; s < 2048; s += TPB) {
                        int ln = s & 63, ms = (s >> 6) & 3, kc = s >> 8;
                        int m = ms * 16 + (ln & 15);
                        int kg = c * 256 + kc * 32 + ((ln >> 4) << 3);
                        const float* src = (l == 0)
                            ? x  + ((size_t)(m * S_ + t)) * H_ + kg
                            : X1 + ((size_t)(t * B_ + m)) * H_ + kg;
                        float4 v0 = *(const float4*)src;
                        float4 v1 = *(const float4*)(src + 4);
                        float vv[8] = {v0.x, v0.y, v0.z, v0.w, v1.x, v1.y, v1.z, v1.w};
                        short8 hi, lo;
                        #pragma unroll
                        for (int j = 0; j < 8; ++j) {
                            unsigned short hb = f2bf(vv[j]);
                            hi[j] = (short)hb; lo[j] = (short)f2bf(vv[j] - bf2f(hb));
                        }
                        *(short8*)&lds[A_HI + s * 8] = hi;
                        *(short8*)&lds[A_LO + s * 8] = lo;
                    }
                } else {       // h-part: bypass global_load_lds from pre-split pub
                    #pragma unroll
                    for (int i = 0; i < 8; ++i) {
                        int sg = wave * 8 + i;           // (kc*4+ms)
                        int kc = sg >> 2, ms = sg & 3;
                        int m  = ms * 16 + (lane & 15);
                        int kh = (c - 4) * 256 + kc * 32 + ((lane >> 4) << 3);
                        GLL(h_hi + m * H_ + kh, &lds[A_HI + sg * 512]);
                        GLL(h_lo + m * H_ + kh, &lds[A_LO + sg * 512]);
                    }
                }
                __syncthreads();
                #pragma unroll
                for (int kk = 0; kk < 8; ++kk) {
                    int kg = c * 8 + kk;
                    short8 bh_ = *(short8*)&lds[WRZ_HI + (((kg * 4 + q) * 8) + (lane & 7)) * 8];
                    short8 bl_ = *(short8*)&lds[WRZ_LO + (((kg * 4 + q) * 8) + (lane & 7)) * 8];
                    short8 ah  = *(short8*)&lds[A_HI + ((kk * 4 + wave) * 64 + lane) * 8];
                    short8 al  = *(short8*)&lds[A_LO + ((kk * 4 + wave) * 64 + lane) * 8];
                    acc = __builtin_amdgcn_mfma_f32_16x16x32_bf16(ah, bh_, acc, 0, 0, 0);
                    acc = __builtin_amdgcn_mfma_f32_16x16x32_bf16(al, bh_, acc, 0, 0, 0);
                    acc = __builtin_amdgcn_mfma_f32_16x16x32_bf16(ah, bl_, acc, 0, 0, 0);
                }
                __syncthreads();
            }
            // epilogue A: sigmoid; publish rh (bypass), keep z private
            if (jc < 8) {
                bool isr = jc < 4;
                int cloc = jc & 3;
                int col = c0 + cloc;
                float bias = isr ? brv : bzv;
                #pragma unroll
                for (int i = 0; i < 4; ++i) {
                    int m = wave * 16 + q * 4 + i;
                    float gt = sigm(acc[i] + bias);
                    if (isr) {
                        float rh = gt * hp[(m << 2) | cloc];
                        unsigned short hb = f2bf(rh);
                        store_short_bypass(rh_hi + m * H_ + col, hb);
                        store_short_bypass(rh_lo + m * H_ + col, f2bf(rh - bf2f(hb)));
                    } else {
                        zp[(m << 2) | cloc] = gt;
                    }
                }
            }
            gbar(bar, grp);

            // =================== Phase B: n gate + h update ===================
            acc = (f32x4){0.f, 0.f, 0.f, 0.f};
            for (int c = 0; c < 8; ++c) {
                if (c < 4) {
                    for (int s = threadIdx.x; s < 2048; s += TPB) {
                        int ln = s & 63, ms = (s >> 6) & 3, kc = s >> 8;
                        int m = ms * 16 + (ln & 15);
                        int kg = c * 256 + kc * 32 + ((ln >> 4) << 3);
                        const float* src = (l == 0)
                            ? x  + ((size_t)(m * S_ + t)) * H_ + kg
                            : X1 + ((size_t)(t * B_ + m)) * H_ + kg;
                        float4 v0 = *(const float4*)src;
                        float4 v1 = *(const float4*)(src + 4);
                        float vv[8] = {v0.x, v0.y, v0.z, v0.w, v1.x, v1.y, v1.z, v1.w};
                        short8 hi, lo;
                        #pragma unroll
                        for (int j = 0; j < 8; ++j) {
                            unsigned short hb = f2bf(vv[j]);
                            hi[j] = (short)hb; lo[j] = (short)f2bf(vv[j] - bf2f(hb));
                        }
                        *(short8*)&lds[A_HI + s * 8] = hi;
                        *(short8*)&lds[A_LO + s * 8] = lo;
                    }
                } else {
                    #pragma unroll
                    for (int i = 0; i < 8; ++i) {
                        int sg = wave * 8 + i;
                        int kc = sg >> 2, ms = sg & 3;
                        int m  = ms * 16 + (lane & 15);
                        int kh = (c - 4) * 256 + kc * 32 + ((lane >> 4) << 3);
                        GLL(rh_hi + m * H_ + kh, &lds[A_HI + sg * 512]);
                        GLL(rh_lo + m * H_ + kh, &lds[A_LO + sg * 512]);
                    }
                }
                __syncthreads();
                #pragma unroll
                for (int kk = 0; kk < 8; ++kk) {
                    int kg = c * 8 + kk;
                    short8 bh_ = *(short8*)&lds[WN_HI + (((kg * 4 + q) * 4) + (lane & 3)) * 8];
                    short8 bl_ = *(short8*)&lds[WN_LO + (((kg * 4 + q) * 4) + (lane & 3)) * 8];
                    short8 ah  = *(short8*)&lds[A_HI + ((kk * 4 + wave) * 64 + lane) * 8];
                    short8 al  = *(short8*)&lds[A_LO + ((kk * 4 + wave) * 64 + lane) * 8];
                    acc = __builtin_amdgcn_mfma_f32_16x16x32_bf16(ah, bh_, acc, 0, 0, 0);
                    acc = __builtin_amdgcn_mfma_f32_16x16x32_bf16(al, bh_, acc, 0, 0, 0);
                    acc = __builtin_amdgcn_mfma_f32_16x16x32_bf16(ah, bl_, acc, 0, 0, 0);
                }
                __syncthreads();
            }
            // epilogue B: tanh, h update, publish h, write X1/out
            if (jc < 4) {
                int col = c0 + jc;
                #pragma unroll
                for (int i = 0; i < 4; ++i) {
                    int m = wave * 16 + q * 4 + i;
                    float nv = tanhf(acc[i] + bhv);
                    float zz = zp[(m << 2) | jc];
                    float ho = hp[(m << 2) | jc];
                    float hn = (1.0f - zz) * nv + zz * ho;
                    hp[(m << 2) | jc] = hn;
                    unsigned short hb = f2bf(hn);
                    store_short_bypass(h_hi + m * H_ + col, hb);
                    store_short_bypass(h_lo + m * H_ + col, f2bf(hn - bf2f(hb)));
                    if (l == 0) X1[((size_t)(t * B_ + m)) * H_ + col] = hn;
                    else        out[((size_t)(m * S_ + t)) * H_ + col] = hn;
                }
            }
            gbar(bar, grp);
        }
        if (l == 0) {
            __threadfence();   // one full agent fence per layer: flush X1 to LLC
            waitcnt0();
        }
    }
}

extern "C" void kernel_launch(void* const* d_in, const int* in_sizes, int n_in,
                              void* d_out, int out_size, void* d_ws, size_t ws_size,
                              hipStream_t stream) {
    const float* x  = (const float*)d_in[0];
    const float* Wr = (const float*)d_in[1];
    const float* Wz = (const float*)d_in[2];
    const float* Wh = (const float*)d_in[3];
    const float* br = (const float*)d_in[4];
    const float* bz = (const float*)d_in[5];
    const float* bh = (const float*)d_in[6];
    float* out = (float*)d_out;

    char* ws = (char*)d_ws;
    unsigned* bar        = (unsigned*)ws;                    // 4 KB
    unsigned short* h_hi = (unsigned short*)(ws + 4096);     // 128 KB each
    unsigned short* h_lo = (unsigned short*)(ws + 135168);
    unsigned short* rhhi = (unsigned short*)(ws + 266240);
    unsigned short* rhlo = (unsigned short*)(ws + 397312);
    float* hpriv         = (float*)(ws + 528384);            // 256 KB
    float* zpriv         = (float*)(ws + 790528);            // 256 KB
    float* X1            = (float*)(ws + (2u << 20));        // 128 MB

    hipMemsetAsync(d_ws, 0, 4096, stream);   // barrier state
    gru_fk<<<NBLK, TPB, 0, stream>>>(x, Wr, Wz, Wh, br, bz, bh, out,
                                     h_hi, h_lo, rhhi, rhlo, hpriv, zpriv, X1, bar);
}